// Round 7
// baseline (560.400 us; speedup 1.0000x reference)
//
#include <hip/hip_runtime.h>
#include <hip/hip_cooperative_groups.h>
#include <hip/hip_fp16.h>

namespace cg = cooperative_groups;

#define N_NODES 50000
#define N_EDGES 800000
#define D_FEAT  64
#define CAP     64                      // fixed slots per node (Poisson(16) max deg ~45)
#define GRID_B  1024
#define BLOCK_T 256
#define NTHREADS (GRID_B * BLOCK_T)     // 262144
#define SPILL_CAP 131072                // 1 MB guarantee net (normally 0 used)

// ---------------------------------------------------------------------------
// Round 7: single cooperative dispatch (tests the launch-gap hypothesis) with
// fixed-capacity per-node CSR (kills hist+alloc passes entirely).
//   S0: zero cnt
//   S1: fill: pos=atomicAdd(&cnt[d],1); csr[d*64+pos]=(src<<16|fp16(w));
//       overflow (never in practice) -> spill list
//   S2: clamp+pad each node's segment to x4 (zero-weight entries)
//   S3: pull: one wave per node (persistent, 4096 waves), uint4 entry loads,
//       8 coalesced 256B queue-row gathers in flight, single 256B store
//   S4: spill fixup via atomics (normally zero iterations)
// ---------------------------------------------------------------------------

__device__ __forceinline__ unsigned pack_entry(unsigned s, float w) {
    return (s << 16) | (unsigned)__half_as_ushort(__float2half(w));
}
__device__ __forceinline__ float entry_w(unsigned e) {
    return __half2float(__ushort_as_half((unsigned short)(e & 0xffffu)));
}

__global__ void __launch_bounds__(BLOCK_T, 4)
fused_kernel(const float* __restrict__ queue, const float* __restrict__ weight,
             const int* __restrict__ src, const int* __restrict__ dst,
             float* __restrict__ out, unsigned* __restrict__ csr,
             int* __restrict__ cnt, uint2* __restrict__ spill,
             int* __restrict__ spillcnt) {
    cg::grid_group grid = cg::this_grid();
    const int tid = (int)(blockIdx.x * BLOCK_T + threadIdx.x);

    // S0: zero counters ----------------------------------------------------
    for (int i = tid; i < N_NODES; i += NTHREADS) cnt[i] = 0;
    if (tid == 0) *spillcnt = 0;
    grid.sync();

    // S1: fill fixed-cap slots (4 independent atomic->store chains/thread) --
    for (int t = tid; t < N_EDGES / 4; t += NTHREADS) {
        const int4   s4 = reinterpret_cast<const int4*>(src)[t];
        const int4   d4 = reinterpret_cast<const int4*>(dst)[t];
        const float4 w4 = reinterpret_cast<const float4*>(weight)[t];
        const int   ss[4] = {s4.x, s4.y, s4.z, s4.w};
        const int   dd[4] = {d4.x, d4.y, d4.z, d4.w};
        const float ww[4] = {w4.x, w4.y, w4.z, w4.w};
#pragma unroll
        for (int j = 0; j < 4; ++j) {
            int pos = atomicAdd(&cnt[dd[j]], 1);
            if (pos < CAP) {
                csr[(size_t)dd[j] * CAP + pos] = pack_entry((unsigned)ss[j], ww[j]);
            } else {
                int sp = atomicAdd(spillcnt, 1);
                if (sp < SPILL_CAP)
                    spill[sp] = make_uint2((unsigned)ss[j] | ((unsigned)dd[j] << 16),
                                           __float_as_uint(ww[j]));
            }
        }
    }
    grid.sync();

    // S2: clamp + pad segments to multiple of 4 ----------------------------
    for (int i = tid; i < N_NODES; i += NTHREADS) {
        int c = cnt[i];
        if (c > CAP) c = CAP;
        int c4 = (c + 3) & ~3;
        unsigned* p = csr + (size_t)i * CAP;
        for (int k = c; k < c4; ++k) p[k] = 0u;   // src=0, w=fp16(0)
        cnt[i] = c4;
    }
    grid.sync();

    // S3: pull — one wave per node, 8 gathers in flight --------------------
    const int wave = tid >> 6, lane = tid & 63;
    const int nwaves = NTHREADS >> 6;             // 4096
    for (int node = wave; node < N_NODES; node += nwaves) {
        const unsigned* p = csr + (size_t)node * CAP;
        const int n4 = cnt[node];
        float acc = 0.0f;
        int i = 0;
        for (; i + 8 <= n4; i += 8) {
            uint4 ea = *reinterpret_cast<const uint4*>(p + i);      // wave-uniform
            uint4 eb = *reinterpret_cast<const uint4*>(p + i + 4);
            float q0 = queue[(size_t)(ea.x >> 16) * D_FEAT + lane]; // coalesced 256B
            float q1 = queue[(size_t)(ea.y >> 16) * D_FEAT + lane];
            float q2 = queue[(size_t)(ea.z >> 16) * D_FEAT + lane];
            float q3 = queue[(size_t)(ea.w >> 16) * D_FEAT + lane];
            float q4 = queue[(size_t)(eb.x >> 16) * D_FEAT + lane];
            float q5 = queue[(size_t)(eb.y >> 16) * D_FEAT + lane];
            float q6 = queue[(size_t)(eb.z >> 16) * D_FEAT + lane];
            float q7 = queue[(size_t)(eb.w >> 16) * D_FEAT + lane];
            acc = fmaf(q0, entry_w(ea.x), acc);
            acc = fmaf(q1, entry_w(ea.y), acc);
            acc = fmaf(q2, entry_w(ea.z), acc);
            acc = fmaf(q3, entry_w(ea.w), acc);
            acc = fmaf(q4, entry_w(eb.x), acc);
            acc = fmaf(q5, entry_w(eb.y), acc);
            acc = fmaf(q6, entry_w(eb.z), acc);
            acc = fmaf(q7, entry_w(eb.w), acc);
        }
        for (; i < n4; i += 4) {
            uint4 ea = *reinterpret_cast<const uint4*>(p + i);
            float q0 = queue[(size_t)(ea.x >> 16) * D_FEAT + lane];
            float q1 = queue[(size_t)(ea.y >> 16) * D_FEAT + lane];
            float q2 = queue[(size_t)(ea.z >> 16) * D_FEAT + lane];
            float q3 = queue[(size_t)(ea.w >> 16) * D_FEAT + lane];
            acc = fmaf(q0, entry_w(ea.x), acc);
            acc = fmaf(q1, entry_w(ea.y), acc);
            acc = fmaf(q2, entry_w(ea.z), acc);
            acc = fmaf(q3, entry_w(ea.w), acc);
        }
        out[(size_t)node * D_FEAT + lane] = acc;  // every node written once
    }
    grid.sync();

    // S4: spill fixup (normally zero iterations) ---------------------------
    const int nsp = min(*spillcnt, SPILL_CAP);
    for (int i = tid; i < nsp * 16; i += NTHREADS) {
        int e = i >> 4;
        int c = (i & 15) << 2;
        uint2 u = spill[e];
        unsigned s = u.x & 0xffffu, d = u.x >> 16;
        float w = __uint_as_float(u.y);
        const float4 q = *reinterpret_cast<const float4*>(queue + (size_t)s * D_FEAT + c);
        float* o = out + (size_t)d * D_FEAT + c;
        atomicAdd(o + 0, q.x * w);
        atomicAdd(o + 1, q.y * w);
        atomicAdd(o + 2, q.z * w);
        atomicAdd(o + 3, q.w * w);
    }
}

// --- Fallback (round-1 scatter) if ws_size is ever too small ---------------
__global__ void __launch_bounds__(256)
scatter_add_kernel(const float* __restrict__ queue,
                   const float* __restrict__ weight,
                   const int* __restrict__ src,
                   const int* __restrict__ dst,
                   float* __restrict__ out) {
    long long tid = (long long)blockIdx.x * blockDim.x + threadIdx.x;
    int e = (int)(tid >> 4);
    int c = ((int)tid & 15) << 2;
    if (e >= N_EDGES) return;
    int s = src[e], d = dst[e];
    float w = weight[e];
    const float4 q = *reinterpret_cast<const float4*>(queue + (size_t)s * D_FEAT + c);
    float* o = out + (size_t)d * D_FEAT + c;
    atomicAdd(o + 0, q.x * w);
    atomicAdd(o + 1, q.y * w);
    atomicAdd(o + 2, q.z * w);
    atomicAdd(o + 3, q.w * w);
}

extern "C" void kernel_launch(void* const* d_in, const int* in_sizes, int n_in,
                              void* d_out, int out_size, void* d_ws, size_t ws_size,
                              hipStream_t stream) {
    const float* queue  = (const float*)d_in[0];
    const float* weight = (const float*)d_in[1];
    const int*   src    = (const int*)d_in[2];
    const int*   dst    = (const int*)d_in[3];
    float* out = (float*)d_out;

    // Workspace layout:
    //   csr:      N_NODES*CAP unsigned  (12.8 MB, 16B-aligned base)
    //   spill:    SPILL_CAP uint2       (1 MB)
    //   cnt:      N_NODES int
    //   spillcnt: 1 int
    const size_t csr_bytes   = (size_t)N_NODES * CAP * sizeof(unsigned);
    const size_t spill_bytes = (size_t)SPILL_CAP * sizeof(uint2);
    const size_t need = csr_bytes + spill_bytes + (size_t)(N_NODES + 1) * sizeof(int);

    if (ws_size < need) {  // safety fallback: round-1 scatter path
        hipMemsetAsync(out, 0, (size_t)out_size * sizeof(float), stream);
        const long long total = (long long)N_EDGES * 16;
        scatter_add_kernel<<<(int)((total + 255) / 256), 256, 0, stream>>>(
            queue, weight, src, dst, out);
        return;
    }

    char* ws = (char*)d_ws;
    unsigned* csr  = (unsigned*)ws;
    uint2* spill   = (uint2*)(ws + csr_bytes);
    int* cnt       = (int*)(ws + csr_bytes + spill_bytes);
    int* spillcnt  = cnt + N_NODES;

    void* args[] = {(void*)&queue, (void*)&weight, (void*)&src, (void*)&dst,
                    (void*)&out, (void*)&csr, (void*)&cnt, (void*)&spill,
                    (void*)&spillcnt};
    hipLaunchCooperativeKernel((const void*)fused_kernel, dim3(GRID_B),
                               dim3(BLOCK_T), args, 0, stream);
}

// Round 8
// 157.615 us; speedup vs baseline: 3.5555x; 3.5555x over previous
//
#include <hip/hip_runtime.h>
#include <hip/hip_fp16.h>

#define N_NODES 50000
#define N_EDGES 800000
#define D_FEAT  64
#define CAP     32                      // slots/node: 128B = 2 lines; P(deg>32)~1e-5
#define SPILL_CAP 262144                // 2 MB; input is Poisson(16) -> ~0 used

// ---------------------------------------------------------------------------
// Round 8: R4 pipeline minus hist/alloc/pad. 3 dispatches.
//   1. memset cnt+spillcnt (0.2 MB)
//   2. fill:  pos=atomicAdd(&cnt[d],1); pos<32 -> csr[d*32+pos]=(src<<16|fp16 w)
//             else spill list. 50K cursors x ~16 ops: no serialization regime
//             (R6 showed 782 cursors x 1K ops = 190us disaster).
//   3. pull:  one wave/node. uint4 wave-uniform entry loads, 8 coalesced 256B
//             queue-row gathers in flight, in-register tail masking (no pad
//             pass), wave-uniform spill scan (normally 0), single 256B store.
// ---------------------------------------------------------------------------

__device__ __forceinline__ unsigned pack_entry(unsigned s, float w) {
    return (s << 16) | (unsigned)__half_as_ushort(__float2half(w));
}
__device__ __forceinline__ float entry_w(unsigned e) {
    return __half2float(__ushort_as_half((unsigned short)(e & 0xffffu)));
}

__global__ void __launch_bounds__(256)
fill_kernel(const int* __restrict__ src, const int* __restrict__ dst,
            const float* __restrict__ weight, int* __restrict__ cnt,
            unsigned* __restrict__ csr, uint2* __restrict__ spill,
            int* __restrict__ spillcnt) {
    int t = blockIdx.x * blockDim.x + threadIdx.x;
    if (t * 4 >= N_EDGES) return;
    const int4   s4 = reinterpret_cast<const int4*>(src)[t];
    const int4   d4 = reinterpret_cast<const int4*>(dst)[t];
    const float4 w4 = reinterpret_cast<const float4*>(weight)[t];
    const int   ss[4] = {s4.x, s4.y, s4.z, s4.w};
    const int   dd[4] = {d4.x, d4.y, d4.z, d4.w};
    const float ww[4] = {w4.x, w4.y, w4.z, w4.w};
#pragma unroll
    for (int j = 0; j < 4; ++j) {
        int pos = atomicAdd(&cnt[dd[j]], 1);
        if (pos < CAP) {
            csr[(size_t)dd[j] * CAP + pos] = pack_entry((unsigned)ss[j], ww[j]);
        } else {
            int sp = atomicAdd(spillcnt, 1);
            if (sp < SPILL_CAP)
                spill[sp] = make_uint2((unsigned)ss[j] | ((unsigned)dd[j] << 16),
                                       __float_as_uint(ww[j]));
        }
    }
}

// One wave per node; 4 nodes per 256-thread block.
__global__ void __launch_bounds__(256)
pull_kernel(const float* __restrict__ queue, const unsigned* __restrict__ csr,
            const int* __restrict__ cnt, const uint2* __restrict__ spill,
            const int* __restrict__ spillcnt, float* __restrict__ out) {
    const int node = blockIdx.x * 4 + (threadIdx.x >> 6);
    const int lane = threadIdx.x & 63;
    if (node >= N_NODES) return;

    const unsigned* p = csr + (size_t)node * CAP;
    const int c = min(cnt[node], CAP);

    float acc = 0.0f;
    int i = 0;
    for (; i + 8 <= c; i += 8) {                    // all 8 valid
        uint4 ea = *reinterpret_cast<const uint4*>(p + i);
        uint4 eb = *reinterpret_cast<const uint4*>(p + i + 4);
        float q0 = queue[(size_t)(ea.x >> 16) * D_FEAT + lane];
        float q1 = queue[(size_t)(ea.y >> 16) * D_FEAT + lane];
        float q2 = queue[(size_t)(ea.z >> 16) * D_FEAT + lane];
        float q3 = queue[(size_t)(ea.w >> 16) * D_FEAT + lane];
        float q4 = queue[(size_t)(eb.x >> 16) * D_FEAT + lane];
        float q5 = queue[(size_t)(eb.y >> 16) * D_FEAT + lane];
        float q6 = queue[(size_t)(eb.z >> 16) * D_FEAT + lane];
        float q7 = queue[(size_t)(eb.w >> 16) * D_FEAT + lane];
        acc = fmaf(q0, entry_w(ea.x), acc);
        acc = fmaf(q1, entry_w(ea.y), acc);
        acc = fmaf(q2, entry_w(ea.z), acc);
        acc = fmaf(q3, entry_w(ea.w), acc);
        acc = fmaf(q4, entry_w(eb.x), acc);
        acc = fmaf(q5, entry_w(eb.y), acc);
        acc = fmaf(q6, entry_w(eb.z), acc);
        acc = fmaf(q7, entry_w(eb.w), acc);
    }
    for (; i < c; i += 4) {                         // masked tail group
        uint4 ea = *reinterpret_cast<const uint4*>(p + i);
        unsigned e0 = (i + 0 < c) ? ea.x : 0u;      // masked: src=0, w=fp16(0)
        unsigned e1 = (i + 1 < c) ? ea.y : 0u;
        unsigned e2 = (i + 2 < c) ? ea.z : 0u;
        unsigned e3 = (i + 3 < c) ? ea.w : 0u;
        float q0 = queue[(size_t)(e0 >> 16) * D_FEAT + lane];
        float q1 = queue[(size_t)(e1 >> 16) * D_FEAT + lane];
        float q2 = queue[(size_t)(e2 >> 16) * D_FEAT + lane];
        float q3 = queue[(size_t)(e3 >> 16) * D_FEAT + lane];
        acc = fmaf(q0, entry_w(e0), acc);
        acc = fmaf(q1, entry_w(e1), acc);
        acc = fmaf(q2, entry_w(e2), acc);
        acc = fmaf(q3, entry_w(e3), acc);
    }

    // Spill edges for this node (normally zero; one cached uniform load).
    const int nsp = min(*spillcnt, SPILL_CAP);
    for (int k = 0; k < nsp; ++k) {
        uint2 u = spill[k];
        if ((u.x >> 16) == (unsigned)node)
            acc = fmaf(queue[(size_t)(u.x & 0xffffu) * D_FEAT + lane],
                       __uint_as_float(u.y), acc);
    }

    out[(size_t)node * D_FEAT + lane] = acc;        // every node written once
}

// --- Fallback (round-1 scatter) if ws_size is ever too small ---------------
__global__ void __launch_bounds__(256)
scatter_add_kernel(const float* __restrict__ queue,
                   const float* __restrict__ weight,
                   const int* __restrict__ src,
                   const int* __restrict__ dst,
                   float* __restrict__ out) {
    long long tid = (long long)blockIdx.x * blockDim.x + threadIdx.x;
    int e = (int)(tid >> 4);
    int c = ((int)tid & 15) << 2;
    if (e >= N_EDGES) return;
    int s = src[e], d = dst[e];
    float w = weight[e];
    const float4 q = *reinterpret_cast<const float4*>(queue + (size_t)s * D_FEAT + c);
    float* o = out + (size_t)d * D_FEAT + c;
    atomicAdd(o + 0, q.x * w);
    atomicAdd(o + 1, q.y * w);
    atomicAdd(o + 2, q.z * w);
    atomicAdd(o + 3, q.w * w);
}

extern "C" void kernel_launch(void* const* d_in, const int* in_sizes, int n_in,
                              void* d_out, int out_size, void* d_ws, size_t ws_size,
                              hipStream_t stream) {
    const float* queue  = (const float*)d_in[0];
    const float* weight = (const float*)d_in[1];
    const int*   src    = (const int*)d_in[2];
    const int*   dst    = (const int*)d_in[3];
    float* out = (float*)d_out;

    // Workspace layout:
    //   csr:      N_NODES*CAP unsigned (6.4 MB, 16B-aligned)
    //   spill:    SPILL_CAP uint2      (2 MB)
    //   cnt:      N_NODES int   \ zeroed together
    //   spillcnt: 1 int         /
    const size_t csr_bytes   = (size_t)N_NODES * CAP * sizeof(unsigned);
    const size_t spill_bytes = (size_t)SPILL_CAP * sizeof(uint2);
    const size_t need = csr_bytes + spill_bytes + (size_t)(N_NODES + 1) * sizeof(int);

    if (ws_size < need) {  // safety fallback: round-1 scatter path
        hipMemsetAsync(out, 0, (size_t)out_size * sizeof(float), stream);
        const long long total = (long long)N_EDGES * 16;
        scatter_add_kernel<<<(int)((total + 255) / 256), 256, 0, stream>>>(
            queue, weight, src, dst, out);
        return;
    }

    char* ws = (char*)d_ws;
    unsigned* csr = (unsigned*)ws;
    uint2* spill  = (uint2*)(ws + csr_bytes);
    int* cnt      = (int*)(ws + csr_bytes + spill_bytes);
    int* spillcnt = cnt + N_NODES;

    hipMemsetAsync(cnt, 0, (size_t)(N_NODES + 1) * sizeof(int), stream);

    fill_kernel<<<(N_EDGES / 4 + 255) / 256, 256, 0, stream>>>(
        src, dst, weight, cnt, csr, spill, spillcnt);
    pull_kernel<<<(N_NODES + 3) / 4, 256, 0, stream>>>(
        queue, csr, cnt, spill, spillcnt, out);
}

// Round 9
// 147.337 us; speedup vs baseline: 3.8035x; 1.0698x over previous
//
#include <hip/hip_runtime.h>
#include <hip/hip_fp16.h>

#define N_NODES 50000
#define N_EDGES 800000
#define D_FEAT  64
#define CAP     32                      // slots/node: 128B = 2 lines; P(deg>32)~1e-5
#define SPILL_CAP 262144                // 2 MB; input is Poisson(16) -> ~0 used
#define FILL_BLOCKS 2048                // 8 partitions x 256 blocks
#define NODES_PER_PART 6250             // 50000 / 8
#define PART_MAGIC 687195ull            // ceil(2^32 / 6250); exact for dst<2^16

// ---------------------------------------------------------------------------
// Round 9: XCD-partitioned fill (kills the 8x partial-line write-back amp).
//   1. memset cnt+spillcnt
//   2. fill:  block b owns partition p = b&7 (round-robin blockIdx->XCD).
//             Each partition's 256 blocks stride the FULL edge list (8x read
//             amp, L3-served) but only commit edges with dst/6250 == p.
//             => each node's csr/cnt lines are touched by ONE XCD's L2 only:
//             lines fill completely before writeback (~5 MB vs 48 MB).
//   3. pull:  unchanged from R8 (one wave/node, 8 gathers in flight,
//             in-register tail masking, wave-uniform spill scan).
// ---------------------------------------------------------------------------

__device__ __forceinline__ unsigned pack_entry(unsigned s, float w) {
    return (s << 16) | (unsigned)__half_as_ushort(__float2half(w));
}
__device__ __forceinline__ float entry_w(unsigned e) {
    return __half2float(__ushort_as_half((unsigned short)(e & 0xffffu)));
}

__global__ void __launch_bounds__(256)
fill_kernel(const int* __restrict__ src, const int* __restrict__ dst,
            const float* __restrict__ weight, int* __restrict__ cnt,
            unsigned* __restrict__ csr, uint2* __restrict__ spill,
            int* __restrict__ spillcnt) {
    const int part = blockIdx.x & 7;          // XCD id under round-robin dispatch
    const int bip  = blockIdx.x >> 3;         // block index within partition
    const int nq   = N_EDGES / 4;             // 200000 quads
    const int tstride = (FILL_BLOCKS / 8) * 256;  // 65536 threads per partition

    for (int t = bip * 256 + threadIdx.x; t < nq; t += tstride) {
        const int4   s4 = reinterpret_cast<const int4*>(src)[t];
        const int4   d4 = reinterpret_cast<const int4*>(dst)[t];
        const float4 w4 = reinterpret_cast<const float4*>(weight)[t];
        const int   ss[4] = {s4.x, s4.y, s4.z, s4.w};
        const int   dd[4] = {d4.x, d4.y, d4.z, d4.w};
        const float ww[4] = {w4.x, w4.y, w4.z, w4.w};
#pragma unroll
        for (int j = 0; j < 4; ++j) {
            const int p = (int)(((unsigned long long)(unsigned)dd[j] * PART_MAGIC) >> 32);
            if (p != part) continue;          // not my XCD's dst range
            int pos = atomicAdd(&cnt[dd[j]], 1);
            if (pos < CAP) {
                csr[(size_t)dd[j] * CAP + pos] = pack_entry((unsigned)ss[j], ww[j]);
            } else {
                int sp = atomicAdd(spillcnt, 1);
                if (sp < SPILL_CAP)
                    spill[sp] = make_uint2((unsigned)ss[j] | ((unsigned)dd[j] << 16),
                                           __float_as_uint(ww[j]));
            }
        }
    }
}

// One wave per node; 4 nodes per 256-thread block. (unchanged from R8)
__global__ void __launch_bounds__(256)
pull_kernel(const float* __restrict__ queue, const unsigned* __restrict__ csr,
            const int* __restrict__ cnt, const uint2* __restrict__ spill,
            const int* __restrict__ spillcnt, float* __restrict__ out) {
    const int node = blockIdx.x * 4 + (threadIdx.x >> 6);
    const int lane = threadIdx.x & 63;
    if (node >= N_NODES) return;

    const unsigned* p = csr + (size_t)node * CAP;
    const int c = min(cnt[node], CAP);

    float acc = 0.0f;
    int i = 0;
    for (; i + 8 <= c; i += 8) {
        uint4 ea = *reinterpret_cast<const uint4*>(p + i);
        uint4 eb = *reinterpret_cast<const uint4*>(p + i + 4);
        float q0 = queue[(size_t)(ea.x >> 16) * D_FEAT + lane];
        float q1 = queue[(size_t)(ea.y >> 16) * D_FEAT + lane];
        float q2 = queue[(size_t)(ea.z >> 16) * D_FEAT + lane];
        float q3 = queue[(size_t)(ea.w >> 16) * D_FEAT + lane];
        float q4 = queue[(size_t)(eb.x >> 16) * D_FEAT + lane];
        float q5 = queue[(size_t)(eb.y >> 16) * D_FEAT + lane];
        float q6 = queue[(size_t)(eb.z >> 16) * D_FEAT + lane];
        float q7 = queue[(size_t)(eb.w >> 16) * D_FEAT + lane];
        acc = fmaf(q0, entry_w(ea.x), acc);
        acc = fmaf(q1, entry_w(ea.y), acc);
        acc = fmaf(q2, entry_w(ea.z), acc);
        acc = fmaf(q3, entry_w(ea.w), acc);
        acc = fmaf(q4, entry_w(eb.x), acc);
        acc = fmaf(q5, entry_w(eb.y), acc);
        acc = fmaf(q6, entry_w(eb.z), acc);
        acc = fmaf(q7, entry_w(eb.w), acc);
    }
    for (; i < c; i += 4) {                         // masked tail group
        uint4 ea = *reinterpret_cast<const uint4*>(p + i);
        unsigned e0 = (i + 0 < c) ? ea.x : 0u;
        unsigned e1 = (i + 1 < c) ? ea.y : 0u;
        unsigned e2 = (i + 2 < c) ? ea.z : 0u;
        unsigned e3 = (i + 3 < c) ? ea.w : 0u;
        float q0 = queue[(size_t)(e0 >> 16) * D_FEAT + lane];
        float q1 = queue[(size_t)(e1 >> 16) * D_FEAT + lane];
        float q2 = queue[(size_t)(e2 >> 16) * D_FEAT + lane];
        float q3 = queue[(size_t)(e3 >> 16) * D_FEAT + lane];
        acc = fmaf(q0, entry_w(e0), acc);
        acc = fmaf(q1, entry_w(e1), acc);
        acc = fmaf(q2, entry_w(e2), acc);
        acc = fmaf(q3, entry_w(e3), acc);
    }

    // Spill edges for this node (normally zero; one cached uniform load).
    const int nsp = min(*spillcnt, SPILL_CAP);
    for (int k = 0; k < nsp; ++k) {
        uint2 u = spill[k];
        if ((u.x >> 16) == (unsigned)node)
            acc = fmaf(queue[(size_t)(u.x & 0xffffu) * D_FEAT + lane],
                       __uint_as_float(u.y), acc);
    }

    out[(size_t)node * D_FEAT + lane] = acc;
}

// --- Fallback (round-1 scatter) if ws_size is ever too small ---------------
__global__ void __launch_bounds__(256)
scatter_add_kernel(const float* __restrict__ queue,
                   const float* __restrict__ weight,
                   const int* __restrict__ src,
                   const int* __restrict__ dst,
                   float* __restrict__ out) {
    long long tid = (long long)blockIdx.x * blockDim.x + threadIdx.x;
    int e = (int)(tid >> 4);
    int c = ((int)tid & 15) << 2;
    if (e >= N_EDGES) return;
    int s = src[e], d = dst[e];
    float w = weight[e];
    const float4 q = *reinterpret_cast<const float4*>(queue + (size_t)s * D_FEAT + c);
    float* o = out + (size_t)d * D_FEAT + c;
    atomicAdd(o + 0, q.x * w);
    atomicAdd(o + 1, q.y * w);
    atomicAdd(o + 2, q.z * w);
    atomicAdd(o + 3, q.w * w);
}

extern "C" void kernel_launch(void* const* d_in, const int* in_sizes, int n_in,
                              void* d_out, int out_size, void* d_ws, size_t ws_size,
                              hipStream_t stream) {
    const float* queue  = (const float*)d_in[0];
    const float* weight = (const float*)d_in[1];
    const int*   src    = (const int*)d_in[2];
    const int*   dst    = (const int*)d_in[3];
    float* out = (float*)d_out;

    // Workspace layout:
    //   csr:      N_NODES*CAP unsigned (6.4 MB, 16B-aligned)
    //   spill:    SPILL_CAP uint2      (2 MB)
    //   cnt:      N_NODES int   \ zeroed together
    //   spillcnt: 1 int         /
    const size_t csr_bytes   = (size_t)N_NODES * CAP * sizeof(unsigned);
    const size_t spill_bytes = (size_t)SPILL_CAP * sizeof(uint2);
    const size_t need = csr_bytes + spill_bytes + (size_t)(N_NODES + 1) * sizeof(int);

    if (ws_size < need) {  // safety fallback: round-1 scatter path
        hipMemsetAsync(out, 0, (size_t)out_size * sizeof(float), stream);
        const long long total = (long long)N_EDGES * 16;
        scatter_add_kernel<<<(int)((total + 255) / 256), 256, 0, stream>>>(
            queue, weight, src, dst, out);
        return;
    }

    char* ws = (char*)d_ws;
    unsigned* csr = (unsigned*)ws;
    uint2* spill  = (uint2*)(ws + csr_bytes);
    int* cnt      = (int*)(ws + csr_bytes + spill_bytes);
    int* spillcnt = cnt + N_NODES;

    hipMemsetAsync(cnt, 0, (size_t)(N_NODES + 1) * sizeof(int), stream);

    fill_kernel<<<FILL_BLOCKS, 256, 0, stream>>>(
        src, dst, weight, cnt, csr, spill, spillcnt);
    pull_kernel<<<(N_NODES + 3) / 4, 256, 0, stream>>>(
        queue, csr, cnt, spill, spillcnt, out);
}

// Round 10
// 145.105 us; speedup vs baseline: 3.8620x; 1.0154x over previous
//
#include <hip/hip_runtime.h>
#include <hip/hip_fp16.h>

#define N_NODES 50000
#define N_EDGES 800000
#define D_FEAT  64
#define CAP     32                      // slots/node: 128B = 2 lines; P(deg>32)~1e-5
#define SPILL_CAP 262144                // 2 MB; input is Poisson(16) -> ~0 used
#define FILL_BLOCKS 2048                // 8 partitions x 256 blocks
#define PART_MAGIC 687195ull            // ceil(2^32 / 6250); exact for dst < 2^16

// ---------------------------------------------------------------------------
// Round 10: fp16 queue for the pull gather + conditional fill loads.
//   1. memset cnt+spillcnt
//   2. fill (XCD-partitioned, 2048 blocks):
//        a) edge loop: load dst quad; only if >=1 edge owned, load src/weight
//           quads (P=0.414 -> partition read traffic 77->47 MB).
//        b) fused convert: queue fp32 -> fp16 (12.8 MB read, 6.4 MB write);
//           6.4 MB fp16 queue fits the 4 MB/XCD L2 far better.
//   3. pull: one wave/node, 16 gathers in flight on 128B fp16 rows,
//      in-register tail masking, wave-uniform spill scan, 256B store.
// ---------------------------------------------------------------------------

__device__ __forceinline__ unsigned pack_entry(unsigned s, float w) {
    return (s << 16) | (unsigned)__half_as_ushort(__float2half(w));
}
__device__ __forceinline__ float entry_w(unsigned e) {
    return __half2float(__ushort_as_half((unsigned short)(e & 0xffffu)));
}
__device__ __forceinline__ int part_of(int d) {
    return (int)(((unsigned long long)(unsigned)d * PART_MAGIC) >> 32);
}

__global__ void __launch_bounds__(256)
fill_kernel(const int* __restrict__ src, const int* __restrict__ dst,
            const float* __restrict__ weight, const float* __restrict__ queue,
            int* __restrict__ cnt, unsigned* __restrict__ csr,
            __half* __restrict__ qh, uint2* __restrict__ spill,
            int* __restrict__ spillcnt) {
    const int part = blockIdx.x & 7;              // XCD id (round-robin dispatch)
    const int bip  = blockIdx.x >> 3;
    const int nq   = N_EDGES / 4;                 // 200000 quads
    const int tstride = (FILL_BLOCKS / 8) * 256;  // 65536 threads/partition

    for (int t = bip * 256 + threadIdx.x; t < nq; t += tstride) {
        const int4 d4 = reinterpret_cast<const int4*>(dst)[t];
        const int p0 = part_of(d4.x), p1 = part_of(d4.y),
                  p2 = part_of(d4.z), p3 = part_of(d4.w);
        if (p0 != part && p1 != part && p2 != part && p3 != part) continue;
        const int4   s4 = reinterpret_cast<const int4*>(src)[t];
        const float4 w4 = reinterpret_cast<const float4*>(weight)[t];
        const int   pp[4] = {p0, p1, p2, p3};
        const int   ss[4] = {s4.x, s4.y, s4.z, s4.w};
        const int   dd[4] = {d4.x, d4.y, d4.z, d4.w};
        const float ww[4] = {w4.x, w4.y, w4.z, w4.w};
#pragma unroll
        for (int j = 0; j < 4; ++j) {
            if (pp[j] != part) continue;
            int pos = atomicAdd(&cnt[dd[j]], 1);
            if (pos < CAP) {
                csr[(size_t)dd[j] * CAP + pos] = pack_entry((unsigned)ss[j], ww[j]);
            } else {
                int sp = atomicAdd(spillcnt, 1);
                if (sp < SPILL_CAP)
                    spill[sp] = make_uint2((unsigned)ss[j] | ((unsigned)dd[j] << 16),
                                           __float_as_uint(ww[j]));
            }
        }
    }

    // Fused queue fp32 -> fp16 convert (coalesced float4 read, 8B write).
    const int gtid = blockIdx.x * 256 + threadIdx.x;      // 524288 threads
    for (int t = gtid; t < N_NODES * D_FEAT / 4; t += FILL_BLOCKS * 256) {
        const float4 q = reinterpret_cast<const float4*>(queue)[t];
        ushort4 h;
        h.x = __half_as_ushort(__float2half(q.x));
        h.y = __half_as_ushort(__float2half(q.y));
        h.z = __half_as_ushort(__float2half(q.z));
        h.w = __half_as_ushort(__float2half(q.w));
        reinterpret_cast<ushort4*>(qh)[t] = h;
    }
}

// One wave per node; 4 nodes per 256-thread block. 16 gathers in flight.
__global__ void __launch_bounds__(256)
pull_kernel(const __half* __restrict__ qh, const float* __restrict__ queue,
            const unsigned* __restrict__ csr, const int* __restrict__ cnt,
            const uint2* __restrict__ spill, const int* __restrict__ spillcnt,
            float* __restrict__ out) {
    const int node = blockIdx.x * 4 + (threadIdx.x >> 6);
    const int lane = threadIdx.x & 63;
    if (node >= N_NODES) return;

    const unsigned* p = csr + (size_t)node * CAP;
    const int c = min(cnt[node], CAP);

    float acc = 0.0f;
    int i = 0;
    for (; i + 16 <= c; i += 16) {                // 16 independent 128B gathers
        uint4 ea = *reinterpret_cast<const uint4*>(p + i);
        uint4 eb = *reinterpret_cast<const uint4*>(p + i + 4);
        uint4 ec = *reinterpret_cast<const uint4*>(p + i + 8);
        uint4 ed = *reinterpret_cast<const uint4*>(p + i + 12);
        float q0  = __half2float(qh[(size_t)(ea.x >> 16) * D_FEAT + lane]);
        float q1  = __half2float(qh[(size_t)(ea.y >> 16) * D_FEAT + lane]);
        float q2  = __half2float(qh[(size_t)(ea.z >> 16) * D_FEAT + lane]);
        float q3  = __half2float(qh[(size_t)(ea.w >> 16) * D_FEAT + lane]);
        float q4  = __half2float(qh[(size_t)(eb.x >> 16) * D_FEAT + lane]);
        float q5  = __half2float(qh[(size_t)(eb.y >> 16) * D_FEAT + lane]);
        float q6  = __half2float(qh[(size_t)(eb.z >> 16) * D_FEAT + lane]);
        float q7  = __half2float(qh[(size_t)(eb.w >> 16) * D_FEAT + lane]);
        float q8  = __half2float(qh[(size_t)(ec.x >> 16) * D_FEAT + lane]);
        float q9  = __half2float(qh[(size_t)(ec.y >> 16) * D_FEAT + lane]);
        float q10 = __half2float(qh[(size_t)(ec.z >> 16) * D_FEAT + lane]);
        float q11 = __half2float(qh[(size_t)(ec.w >> 16) * D_FEAT + lane]);
        float q12 = __half2float(qh[(size_t)(ed.x >> 16) * D_FEAT + lane]);
        float q13 = __half2float(qh[(size_t)(ed.y >> 16) * D_FEAT + lane]);
        float q14 = __half2float(qh[(size_t)(ed.z >> 16) * D_FEAT + lane]);
        float q15 = __half2float(qh[(size_t)(ed.w >> 16) * D_FEAT + lane]);
        acc = fmaf(q0,  entry_w(ea.x), acc);
        acc = fmaf(q1,  entry_w(ea.y), acc);
        acc = fmaf(q2,  entry_w(ea.z), acc);
        acc = fmaf(q3,  entry_w(ea.w), acc);
        acc = fmaf(q4,  entry_w(eb.x), acc);
        acc = fmaf(q5,  entry_w(eb.y), acc);
        acc = fmaf(q6,  entry_w(eb.z), acc);
        acc = fmaf(q7,  entry_w(eb.w), acc);
        acc = fmaf(q8,  entry_w(ec.x), acc);
        acc = fmaf(q9,  entry_w(ec.y), acc);
        acc = fmaf(q10, entry_w(ec.z), acc);
        acc = fmaf(q11, entry_w(ec.w), acc);
        acc = fmaf(q12, entry_w(ed.x), acc);
        acc = fmaf(q13, entry_w(ed.y), acc);
        acc = fmaf(q14, entry_w(ed.z), acc);
        acc = fmaf(q15, entry_w(ed.w), acc);
    }
    for (; i < c; i += 4) {                       // masked tail group
        uint4 ea = *reinterpret_cast<const uint4*>(p + i);
        unsigned e0 = (i + 0 < c) ? ea.x : 0u;    // masked: src=0, w=fp16(0)
        unsigned e1 = (i + 1 < c) ? ea.y : 0u;
        unsigned e2 = (i + 2 < c) ? ea.z : 0u;
        unsigned e3 = (i + 3 < c) ? ea.w : 0u;
        float q0 = __half2float(qh[(size_t)(e0 >> 16) * D_FEAT + lane]);
        float q1 = __half2float(qh[(size_t)(e1 >> 16) * D_FEAT + lane]);
        float q2 = __half2float(qh[(size_t)(e2 >> 16) * D_FEAT + lane]);
        float q3 = __half2float(qh[(size_t)(e3 >> 16) * D_FEAT + lane]);
        acc = fmaf(q0, entry_w(e0), acc);
        acc = fmaf(q1, entry_w(e1), acc);
        acc = fmaf(q2, entry_w(e2), acc);
        acc = fmaf(q3, entry_w(e3), acc);
    }

    // Spill edges for this node (normally zero; fp32 path, uniform load).
    const int nsp = min(*spillcnt, SPILL_CAP);
    for (int k = 0; k < nsp; ++k) {
        uint2 u = spill[k];
        if ((u.x >> 16) == (unsigned)node)
            acc = fmaf(queue[(size_t)(u.x & 0xffffu) * D_FEAT + lane],
                       __uint_as_float(u.y), acc);
    }

    out[(size_t)node * D_FEAT + lane] = acc;
}

// --- Fallback (round-1 scatter) if ws_size is ever too small ---------------
__global__ void __launch_bounds__(256)
scatter_add_kernel(const float* __restrict__ queue,
                   const float* __restrict__ weight,
                   const int* __restrict__ src,
                   const int* __restrict__ dst,
                   float* __restrict__ out) {
    long long tid = (long long)blockIdx.x * blockDim.x + threadIdx.x;
    int e = (int)(tid >> 4);
    int c = ((int)tid & 15) << 2;
    if (e >= N_EDGES) return;
    int s = src[e], d = dst[e];
    float w = weight[e];
    const float4 q = *reinterpret_cast<const float4*>(queue + (size_t)s * D_FEAT + c);
    float* o = out + (size_t)d * D_FEAT + c;
    atomicAdd(o + 0, q.x * w);
    atomicAdd(o + 1, q.y * w);
    atomicAdd(o + 2, q.z * w);
    atomicAdd(o + 3, q.w * w);
}

extern "C" void kernel_launch(void* const* d_in, const int* in_sizes, int n_in,
                              void* d_out, int out_size, void* d_ws, size_t ws_size,
                              hipStream_t stream) {
    const float* queue  = (const float*)d_in[0];
    const float* weight = (const float*)d_in[1];
    const int*   src    = (const int*)d_in[2];
    const int*   dst    = (const int*)d_in[3];
    float* out = (float*)d_out;

    // Workspace layout (16B-aligned blocks):
    //   csr:      N_NODES*CAP unsigned   (6.4 MB)
    //   qh:       N_NODES*D_FEAT __half  (6.4 MB)
    //   spill:    SPILL_CAP uint2        (2 MB)
    //   cnt:      N_NODES int   \ zeroed together
    //   spillcnt: 1 int         /
    const size_t csr_bytes   = (size_t)N_NODES * CAP * sizeof(unsigned);
    const size_t qh_bytes    = (size_t)N_NODES * D_FEAT * sizeof(__half);
    const size_t spill_bytes = (size_t)SPILL_CAP * sizeof(uint2);
    const size_t need = csr_bytes + qh_bytes + spill_bytes
                      + (size_t)(N_NODES + 1) * sizeof(int);

    if (ws_size < need) {  // safety fallback: round-1 scatter path
        hipMemsetAsync(out, 0, (size_t)out_size * sizeof(float), stream);
        const long long total = (long long)N_EDGES * 16;
        scatter_add_kernel<<<(int)((total + 255) / 256), 256, 0, stream>>>(
            queue, weight, src, dst, out);
        return;
    }

    char* ws = (char*)d_ws;
    unsigned* csr = (unsigned*)ws;
    __half* qh    = (__half*)(ws + csr_bytes);
    uint2* spill  = (uint2*)(ws + csr_bytes + qh_bytes);
    int* cnt      = (int*)(ws + csr_bytes + qh_bytes + spill_bytes);
    int* spillcnt = cnt + N_NODES;

    hipMemsetAsync(cnt, 0, (size_t)(N_NODES + 1) * sizeof(int), stream);

    fill_kernel<<<FILL_BLOCKS, 256, 0, stream>>>(
        src, dst, weight, queue, cnt, csr, qh, spill, spillcnt);
    pull_kernel<<<(N_NODES + 3) / 4, 256, 0, stream>>>(
        qh, queue, csr, cnt, spill, spillcnt, out);
}